// Round 14
// baseline (421.632 us; speedup 1.0000x reference)
//
#include <hip/hip_runtime.h>

#define NN 50000
#define NPAD 50048
#define DD 128
#define GG 64
#define NBLK 49   // ceil(NN/1024)

typedef __attribute__((ext_vector_type(8))) short short8;
typedef __attribute__((ext_vector_type(8))) unsigned short ushort8;
typedef __attribute__((ext_vector_type(4))) float f32x4;

__device__ __forceinline__ unsigned short f2bf(float f){
  union { float f; unsigned u; } x; x.f = f;
  unsigned r = x.u + 0x7fffu + ((x.u >> 16) & 1u);
  return (unsigned short)(r >> 16);
}
__device__ __forceinline__ float bf2f(unsigned short h){
  union { unsigned u; float f; } x; x.u = ((unsigned)h) << 16;
  return x.f;
}
// fp16: half-ulp 2^-12
__device__ __forceinline__ unsigned short f2h(float f){
  union { _Float16 h; unsigned short u; } x; x.h = (_Float16)f; return x.u;
}
__device__ __forceinline__ float h2f(unsigned short u){
  union { _Float16 h; unsigned short u; } x; x.u = u; return (float)x.h;
}
__device__ __forceinline__ f32x4 mfma16(short8 a, short8 b, f32x4 c){
  return __builtin_amdgcn_mfma_f32_16x16x32_bf16(a, b, c, 0, 0, 0);
}

__device__ __forceinline__ float wave_reduce_sum(float v){
  #pragma unroll
  for (int off = 32; off; off >>= 1) v += __shfl_xor(v, off, 64);
  return v;
}
__device__ __forceinline__ float wave_reduce_max(float v){
  #pragma unroll
  for (int off = 32; off; off >>= 1) v = fmaxf(v, __shfl_xor(v, off, 64));
  return v;
}

// ---------- fused gather + LayerNorm(l0) + attention dots; writes x fp32 + xhf fp16 ----------
__global__ __launch_bounds__(256) void gather_ln_kernel(const int* __restrict__ ids,
    const float* __restrict__ emb,
    const float* __restrict__ gamma, const float* __restrict__ beta,
    const float* __restrict__ aw,
    float* __restrict__ x, unsigned short* __restrict__ xhf,
    float* __restrict__ sd, float* __restrict__ ss, float* __restrict__ selfsc){
  int n = (blockIdx.x * 256 + threadIdx.x) >> 6;
  int lane = threadIdx.x & 63;
  if (n >= NN) return;
  int id = ids[n];
  float2 v = *(const float2*)&emb[(size_t)id * DD + lane * 2];
  float s  = wave_reduce_sum(v.x + v.y);
  float sq = wave_reduce_sum(v.x * v.x + v.y * v.y);
  float mu  = s * (1.0f / 128.0f);
  float var = sq * (1.0f / 128.0f) - mu * mu;
  float rs  = rsqrtf(var + 1e-5f);
  float2 g = *(const float2*)&gamma[lane * 2];
  float2 b = *(const float2*)&beta[lane * 2];
  float2 y;
  y.x = (v.x - mu) * rs * g.x + b.x;
  y.y = (v.y - mu) * rs * g.y + b.y;
  *(float2*)&x[(size_t)n * DD + lane * 2] = y;
  unsigned pk = (unsigned)f2h(y.x) | ((unsigned)f2h(y.y) << 16);
  ((unsigned*)xhf)[(size_t)n * 64 + lane] = pk;
  float2 a1 = *(const float2*)&aw[lane * 2];
  float2 a2 = *(const float2*)&aw[DD + lane * 2];
  float pd = wave_reduce_sum(y.x * a1.x + y.y * a1.y);
  float ps = wave_reduce_sum(y.x * a2.x + y.y * a2.y);
  if (lane == 0){
    sd[n] = pd; ss[n] = ps;
    float sc = pd + ps;
    selfsc[n] = sc >= 0.f ? sc : 0.2f * sc;
  }
}

// ---------- pack W into MFMA B-fragment order, split bf16 hi/lo ----------
__global__ __launch_bounds__(256) void pack_w_kernel(const float* __restrict__ w1,
    const float* __restrict__ w2, short* __restrict__ wph, short* __restrict__ wpl){
  int i = blockIdx.x * 256 + threadIdx.x;   // 65536 total
  int m = i >> 14, k = (i >> 7) & 127, c = i & 127;
  const float* src = (m & 1) ? w2 : w1;
  float v = src[((size_t)(m >> 1) * 128 + k) * 128 + c];
  unsigned short h = f2bf(v);
  float lo = v - bf2f(h);
  int idx = (m << 14) + ((k >> 3) << 10) + (c << 3) + (k & 7);
  wph[idx] = (short)h;
  wpl[idx] = (short)f2bf(lo);
}

// ---------- CSR build: count with 4-edge ILP ----------
__global__ __launch_bounds__(256) void count_kernel(const int* __restrict__ dst,
    int* __restrict__ cnt, int E, int Q){
  int t = blockIdx.x * 256 + threadIdx.x;
  if (t >= Q) return;
  int e0 = t, e1 = t + Q, e2 = t + 2 * Q, e3 = t + 3 * Q;
  int d0 = (e0 < E) ? dst[e0] : -1;
  int d1 = (e1 < E) ? dst[e1] : -1;
  int d2 = (e2 < E) ? dst[e2] : -1;
  int d3 = (e3 < E) ? dst[e3] : -1;
  if (d0 >= 0) atomicAdd(&cnt[d0], 1);
  if (d1 >= 0) atomicAdd(&cnt[d1], 1);
  if (d2 >= 0) atomicAdd(&cnt[d2], 1);
  if (d3 >= 0) atomicAdd(&cnt[d3], 1);
}

__global__ __launch_bounds__(256) void scan1_kernel(const int* __restrict__ cnt,
    int* __restrict__ rp, int* __restrict__ bsum){
  __shared__ int wsum[4];
  int tid = threadIdx.x, lane = tid & 63, wid = tid >> 6;
  int base = blockIdx.x * 1024 + tid * 4;
  int4 v = {0,0,0,0};
  if (base < NN) v = *(const int4*)&cnt[base];
  int tsum = v.x + v.y + v.z + v.w;
  int incl = tsum;
  #pragma unroll
  for (int off = 1; off < 64; off <<= 1){
    int t = __shfl_up(incl, off, 64);
    if (lane >= off) incl += t;
  }
  if (lane == 63) wsum[wid] = incl;
  __syncthreads();
  int woff = 0;
  for (int w = 0; w < wid; ++w) woff += wsum[w];
  int excl = woff + incl - tsum;
  if (base < NN){
    int4 o;
    o.x = excl; o.y = excl + v.x; o.z = excl + v.x + v.y; o.w = excl + v.x + v.y + v.z;
    *(int4*)&rp[base] = o;
  }
  if (tid == 0) bsum[blockIdx.x] = wsum[0] + wsum[1] + wsum[2] + wsum[3];
}

__global__ __launch_bounds__(64) void scan2_kernel(int* __restrict__ bsum, int* __restrict__ rp){
  int lane = threadIdx.x;
  int v = (lane < NBLK) ? bsum[lane] : 0;
  int incl = v;
  #pragma unroll
  for (int off = 1; off < 64; off <<= 1){
    int t = __shfl_up(incl, off, 64);
    if (lane >= off) incl += t;
  }
  if (lane < NBLK) bsum[lane] = incl - v;
  if (lane == 63) rp[NN] = incl;
}

__global__ __launch_bounds__(256) void scan3_kernel(const int* __restrict__ bsum,
    int* __restrict__ rp, int* __restrict__ cursor){
  int base = blockIdx.x * 1024 + threadIdx.x * 4;
  if (base >= NN) return;
  int add = bsum[blockIdx.x];
  int4 t = *(const int4*)&rp[base];
  t.x += add; t.y += add; t.z += add; t.w += add;
  *(int4*)&rp[base] = t;
  *(int4*)&cursor[base] = t;
}

// ---------- scatter: 4 edges/thread ILP; 4B record {u16 src | fp16 ew} ----------
__global__ __launch_bounds__(256) void scatter_kernel(const int* __restrict__ src,
    const int* __restrict__ dst, const float* __restrict__ ew,
    int* __restrict__ cursor, unsigned* __restrict__ csr, int E, int Q){
  int t = blockIdx.x * 256 + threadIdx.x;
  if (t >= Q) return;
  int e0 = t, e1 = t + Q, e2 = t + 2 * Q, e3 = t + 3 * Q;
  int d0 = (e0 < E) ? dst[e0] : -1;
  int d1 = (e1 < E) ? dst[e1] : -1;
  int d2 = (e2 < E) ? dst[e2] : -1;
  int d3 = (e3 < E) ? dst[e3] : -1;
  unsigned r0 = 0, r1 = 0, r2 = 0, r3 = 0;
  if (d0 >= 0) r0 = (unsigned)src[e0] | ((unsigned)f2h(ew[e0]) << 16);
  if (d1 >= 0) r1 = (unsigned)src[e1] | ((unsigned)f2h(ew[e1]) << 16);
  if (d2 >= 0) r2 = (unsigned)src[e2] | ((unsigned)f2h(ew[e2]) << 16);
  if (d3 >= 0) r3 = (unsigned)src[e3] | ((unsigned)f2h(ew[e3]) << 16);
  int p0 = (d0 >= 0) ? atomicAdd(&cursor[d0], 1) : 0;
  int p1 = (d1 >= 0) ? atomicAdd(&cursor[d1], 1) : 0;
  int p2 = (d2 >= 0) ? atomicAdd(&cursor[d2], 1) : 0;
  int p3 = (d3 >= 0) ? atomicAdd(&cursor[d3], 1) : 0;
  if (d0 >= 0) csr[p0] = r0;
  if (d1 >= 0) csr[p1] = r1;
  if (d2 >= 0) csr[p2] = r2;
  if (d3 >= 0) csr[p3] = r3;
}

// ---------- per-node softmax stats + per-edge weight precompute (split, R8 structure) ----------
__global__ __launch_bounds__(256) void wgt_kernel(
    const int* __restrict__ row_ptr, const unsigned* __restrict__ csr,
    const float* __restrict__ sd, const float* __restrict__ ss,
    const float* __restrict__ selfsc,
    const float* __restrict__ eps_arr, int layer,
    float* __restrict__ csr_w, float* __restrict__ coef){
  int n = (blockIdx.x * 256 + threadIdx.x) >> 6;
  int lane = threadIdx.x & 63;
  if (n >= NN) return;
  int beg = row_ptr[n], end = row_ptr[n + 1];
  float sdn = sd[n];
  float sf = selfsc[n];
  float m = sf;
  for (int j = beg + lane; j < end; j += 64){
    unsigned e = csr[j];
    float sc = sdn + ss[e & 0xFFFFu];
    sc = sc >= 0.f ? sc : 0.2f * sc;
    m = fmaxf(m, sc);
  }
  m = wave_reduce_max(m);
  float dsum = 0.f;
  for (int j = beg + lane; j < end; j += 64){
    unsigned e = csr[j];
    float sc = sdn + ss[e & 0xFFFFu];
    sc = sc >= 0.f ? sc : 0.2f * sc;
    dsum += expf(sc - m);
  }
  dsum = wave_reduce_sum(dsum);
  float exself = expf(sf - m);
  dsum += exself;
  float inv = 1.0f / (dsum + 1e-16f);
  for (int j = beg + lane; j < end; j += 64){
    unsigned e = csr[j];
    float sc = sdn + ss[e & 0xFFFFu];
    sc = sc >= 0.f ? sc : 0.2f * sc;
    csr_w[j] = expf(sc - m) * inv * h2f((unsigned short)(e >> 16));
  }
  if (lane == 0) coef[n] = 1.0f + eps_arr[layer] + exself * inv;
}

// ---------- gather-aggregate (fp16 messages) + GIN self term (fp32); writes bf16 hi/lo ----------
__global__ __launch_bounds__(256) void agg2_kernel(const float* __restrict__ x,
    const unsigned short* __restrict__ xhf,
    const int* __restrict__ row_ptr, const unsigned* __restrict__ csr,
    const float* __restrict__ csr_w,
    const float* __restrict__ coef, short* __restrict__ aggH, short* __restrict__ aggL){
  int n = (blockIdx.x * 256 + threadIdx.x) >> 6;
  int lane = threadIdx.x & 63;
  if (n >= NN) return;
  int grp = lane >> 4, sub = lane & 15;
  int beg = row_ptr[n], end = row_ptr[n + 1];
  float a[8] = {0,0,0,0,0,0,0,0};
  int j = beg + grp;
  for (; j + 4 < end; j += 8){
    int   s0 = csr[j] & 0xFFFFu;     float w0 = csr_w[j];
    int   s1 = csr[j + 4] & 0xFFFFu; float w1 = csr_w[j + 4];
    ushort8 u0 = *(const ushort8*)&xhf[(size_t)s0 * DD + sub * 8];
    ushort8 u1 = *(const ushort8*)&xhf[(size_t)s1 * DD + sub * 8];
    #pragma unroll
    for (int i = 0; i < 8; ++i) a[i] = fmaf(w0, h2f(u0[i]), a[i]);
    #pragma unroll
    for (int i = 0; i < 8; ++i) a[i] = fmaf(w1, h2f(u1[i]), a[i]);
  }
  if (j < end){
    int s0 = csr[j] & 0xFFFFu; float w0 = csr_w[j];
    ushort8 u0 = *(const ushort8*)&xhf[(size_t)s0 * DD + sub * 8];
    #pragma unroll
    for (int i = 0; i < 8; ++i) a[i] = fmaf(w0, h2f(u0[i]), a[i]);
  }
  #pragma unroll
  for (int mask = 16; mask <= 32; mask <<= 1){
    #pragma unroll
    for (int i = 0; i < 8; ++i) a[i] += __shfl_xor(a[i], mask, 64);
  }
  if (grp == 0){
    float c = coef[n];
    const float4* xr = (const float4*)&x[(size_t)n * DD + sub * 8];
    float4 x0 = xr[0], x1 = xr[1];
    a[0] = fmaf(c, x0.x, a[0]); a[1] = fmaf(c, x0.y, a[1]);
    a[2] = fmaf(c, x0.z, a[2]); a[3] = fmaf(c, x0.w, a[3]);
    a[4] = fmaf(c, x1.x, a[4]); a[5] = fmaf(c, x1.y, a[5]);
    a[6] = fmaf(c, x1.z, a[6]); a[7] = fmaf(c, x1.w, a[7]);
    short8 H, L;
    #pragma unroll
    for (int i = 0; i < 8; ++i){
      unsigned short h = f2bf(a[i]);
      H[i] = (short)h;
      L[i] = (short)f2bf(a[i] - bf2f(h));
    }
    *(short8*)&aggH[(size_t)n * DD + sub * 8] = H;
    *(short8*)&aggL[(size_t)n * DD + sub * 8] = L;
  }
}

// ---------- MFMA conv MLP (split-bf16 3-term). R10-measured structure; barriers removed ----------
// Each wave's LDS stripe (rows w*16..w*16+15) is private -> no __syncthreads needed.
template<int MODE>
__global__ __launch_bounds__(256) void mlp_mfma_kernel(
    const short* __restrict__ aH, const short* __restrict__ aL,
    const short* __restrict__ w1h, const short* __restrict__ w1l,
    const short* __restrict__ w2h, const short* __restrict__ w2l,
    const float* __restrict__ B1, const float* __restrict__ B2,
    const float* __restrict__ g2, const float* __restrict__ be2,
    const float* __restrict__ aw2,
    float* __restrict__ xout, unsigned short* __restrict__ xhf,
    float* __restrict__ sd, float* __restrict__ ss,
    float* __restrict__ selfsc){
  __shared__ __align__(16) short hh[64 * DD];
  __shared__ __align__(16) short hl[64 * DD];
  int tid = threadIdx.x;
  int w = tid >> 6, l = tid & 63;
  int g = l >> 4, c16 = l & 15;
  int base = blockIdx.x * 64;
  int rowA = base + w * 16 + c16;

  short8 a1h[4], a1l[4];
  #pragma unroll
  for (int ks = 0; ks < 4; ++ks){
    size_t off = (size_t)rowA * DD + ks * 32 + g * 8;
    a1h[ks] = *(const short8*)(aH + off);
    a1l[ks] = *(const short8*)(aL + off);
  }

  f32x4 acc[8];
  #pragma unroll
  for (int ct = 0; ct < 8; ++ct){
    f32x4 a = {0.f, 0.f, 0.f, 0.f};
    #pragma unroll
    for (int ks = 0; ks < 4; ++ks){
      int bo = (((ks * 4 + g) * 128) + ct * 16 + c16) * 8;
      short8 bh = *(const short8*)(w1h + bo);
      short8 bl = *(const short8*)(w1l + bo);
      a = mfma16(a1h[ks], bh, a);
      a = mfma16(a1l[ks], bh, a);
      a = mfma16(a1h[ks], bl, a);
    }
    acc[ct] = a;
  }

  // epilogue 1: bias + relu, split to bf16 hi/lo in this wave's swizzled LDS stripe
  #pragma unroll
  for (int ct = 0; ct < 8; ++ct){
    int col = ct * 16 + c16;
    float b = B1[col];
    #pragma unroll
    for (int r = 0; r < 4; ++r){
      int rl = w * 16 + g * 4 + r;
      float v = acc[ct][r] + b;
      v = v > 0.f ? v : 0.f;
      unsigned short h = f2bf(v);
      int idx = rl * DD + ((((col >> 3) ^ (rl & 7))) << 3) + (col & 7);
      hh[idx] = (short)h;
      hl[idx] = (short)f2bf(v - bf2f(h));
    }
  }
  // no __syncthreads: stripe is wave-private; compiler inserts lgkmcnt waits

  int rowL = w * 16 + c16;
  short8 a2h[4], a2l[4];
  #pragma unroll
  for (int ks = 0; ks < 4; ++ks){
    int chunk = ks * 4 + g;
    int idx = rowL * DD + ((chunk ^ (rowL & 7)) << 3);
    a2h[ks] = *(const short8*)&hh[idx];
    a2l[ks] = *(const short8*)&hl[idx];
  }

  #pragma unroll
  for (int ct = 0; ct < 8; ++ct){
    f32x4 a = {0.f, 0.f, 0.f, 0.f};
    #pragma unroll
    for (int ks = 0; ks < 4; ++ks){
      int bo = (((ks * 4 + g) * 128) + ct * 16 + c16) * 8;
      short8 bh = *(const short8*)(w2h + bo);
      short8 bl = *(const short8*)(w2l + bo);
      a = mfma16(a2h[ks], bh, a);
      a = mfma16(a2l[ks], bh, a);
      a = mfma16(a2h[ks], bl, a);
    }
    acc[ct] = a;
  }

  #pragma unroll
  for (int ct = 0; ct < 8; ++ct){
    int col = ct * 16 + c16;
    float b = B2[col];
    #pragma unroll
    for (int r = 0; r < 4; ++r){
      float v = acc[ct][r] + b;
      acc[ct][r] = v > 0.f ? v : 0.f;
    }
  }

  if (MODE == 1){
    #pragma unroll
    for (int ct = 0; ct < 8; ++ct){
      int col = ct * 16 + c16;
      #pragma unroll
      for (int r = 0; r < 4; ++r){
        int row = base + w * 16 + g * 4 + r;
        if (row < NN) xout[(size_t)row * DD + col] = acc[ct][r];
      }
    }
  } else {
    float s[4] = {0,0,0,0}, sq[4] = {0,0,0,0};
    #pragma unroll
    for (int ct = 0; ct < 8; ++ct)
      #pragma unroll
      for (int r = 0; r < 4; ++r){ float v = acc[ct][r]; s[r] += v; sq[r] += v * v; }
    #pragma unroll
    for (int off = 1; off < 16; off <<= 1){
      #pragma unroll
      for (int r = 0; r < 4; ++r){
        s[r]  += __shfl_xor(s[r],  off, 64);
        sq[r] += __shfl_xor(sq[r], off, 64);
      }
    }
    float mu[4], rs[4];
    #pragma unroll
    for (int r = 0; r < 4; ++r){
      mu[r] = s[r] * (1.f / 128.f);
      float var = sq[r] * (1.f / 128.f) - mu[r] * mu[r];
      rs[r] = rsqrtf(var + 1e-5f);
    }
    float pd[4] = {0,0,0,0}, ps[4] = {0,0,0,0};
    #pragma unroll
    for (int ct = 0; ct < 8; ++ct){
      int col = ct * 16 + c16;
      float gam = g2[col], bet = be2[col];
      float aa = aw2[col], ab = aw2[DD + col];
      #pragma unroll
      for (int r = 0; r < 4; ++r){
        float y = (acc[ct][r] - mu[r]) * rs[r] * gam + bet;
        acc[ct][r] = y;
        pd[r] += y * aa; ps[r] += y * ab;
      }
    }
    #pragma unroll
    for (int off = 1; off < 16; off <<= 1){
      #pragma unroll
      for (int r = 0; r < 4; ++r){
        pd[r] += __shfl_xor(pd[r], off, 64);
        ps[r] += __shfl_xor(ps[r], off, 64);
      }
    }
    #pragma unroll
    for (int ct = 0; ct < 8; ++ct){
      int col = ct * 16 + c16;
      #pragma unroll
      for (int r = 0; r < 4; ++r){
        int row = base + w * 16 + g * 4 + r;
        if (row < NN){
          float y = acc[ct][r];
          xout[(size_t)row * DD + col] = y;
          xhf[(size_t)row * DD + col] = f2h(y);
        }
      }
    }
    if (c16 == 0){
      #pragma unroll
      for (int r = 0; r < 4; ++r){
        int row = base + w * 16 + g * 4 + r;
        if (row < NN){
          sd[row] = pd[r]; ss[row] = ps[r];
          float sc = pd[r] + ps[r];
          selfsc[row] = sc >= 0.f ? sc : 0.2f * sc;
        }
      }
    }
  }
}

// ---------- global mean pool (16 parts/graph, 4-way unrolled) ----------
__global__ __launch_bounds__(128) void pool_kernel(const float* __restrict__ x,
    const int* __restrict__ batch, float* __restrict__ gsum, int* __restrict__ gcnt){
  int g = blockIdx.x >> 4, part = blockIdx.x & 15;
  int lo = 0, hi = NN;
  while (lo < hi){ int mid = (lo + hi) >> 1; if (batch[mid] < g) lo = mid + 1; else hi = mid; }
  int beg = lo;
  lo = beg; hi = NN;
  while (lo < hi){ int mid = (lo + hi) >> 1; if (batch[mid] < g + 1) lo = mid + 1; else hi = mid; }
  int end = lo;
  int cg = end - beg;
  int rb = beg + (int)((long long)cg * part / 16);
  int re = beg + (int)((long long)cg * (part + 1) / 16);
  int d = threadIdx.x;
  float s0 = 0.f, s1 = 0.f, s2 = 0.f, s3 = 0.f;
  int r = rb;
  for (; r + 3 < re; r += 4){
    s0 += x[(size_t)r * DD + d];
    s1 += x[(size_t)(r + 1) * DD + d];
    s2 += x[(size_t)(r + 2) * DD + d];
    s3 += x[(size_t)(r + 3) * DD + d];
  }
  for (; r < re; ++r) s0 += x[(size_t)r * DD + d];
  float sum = (s0 + s1) + (s2 + s3);
  atomicAdd(&gsum[g * DD + d], sum);
  if (d == 0 && part == 0) gcnt[g] = cg;
}

// ---------- head MLP ----------
__global__ __launch_bounds__(256) void head_kernel(const float* __restrict__ gsum,
    const int* __restrict__ gcnt,
    const float* __restrict__ wh1, const float* __restrict__ bh1,
    const float* __restrict__ wh2, const float* __restrict__ bh2,
    float* __restrict__ outp){
  __shared__ float gm[GG * DD];
  __shared__ float h[GG * 64];
  int tid = threadIdx.x;
  for (int i = tid; i < GG * DD; i += 256){
    int g = i >> 7;
    int c = gcnt[g];
    gm[i] = gsum[i] / (float)(c > 0 ? c : 1);
  }
  __syncthreads();
  for (int i = tid; i < GG * 64; i += 256){
    int r = i >> 6, c = i & 63;
    float a0 = 0.f, a1 = 0.f;
    for (int k = 0; k < DD; k += 2){
      a0 = fmaf(gm[r * DD + k],     wh1[k * 64 + c],       a0);
      a1 = fmaf(gm[r * DD + k + 1], wh1[(k + 1) * 64 + c], a1);
    }
    float v = a0 + a1 + bh1[c];
    h[i] = v > 0.f ? v : 0.f;
  }
  __syncthreads();
  if (tid < GG * 2){
    int r = tid >> 1, c = tid & 1;
    float a = 0.f;
    for (int k = 0; k < 64; ++k) a = fmaf(h[r * 64 + k], wh2[k * 2 + c], a);
    outp[tid] = a + bh2[c];
  }
}

extern "C" void kernel_launch(void* const* d_in, const int* in_sizes, int n_in,
                              void* d_out, int out_size, void* d_ws, size_t ws_size,
                              hipStream_t stream){
  const int*   node_ids    = (const int*)  d_in[0];
  const int*   edge_index  = (const int*)  d_in[1];
  const float* edge_weight = (const float*)d_in[2];
  const int*   batch       = (const int*)  d_in[3];
  const float* emb         = (const float*)d_in[4];
  const float* ln_g        = (const float*)d_in[5];
  const float* ln_b        = (const float*)d_in[6];
  const float* att_w       = (const float*)d_in[7];
  const float* w1          = (const float*)d_in[8];
  const float* b1          = (const float*)d_in[9];
  const float* w2          = (const float*)d_in[10];
  const float* b2          = (const float*)d_in[11];
  const float* eps         = (const float*)d_in[12];
  const float* wh1         = (const float*)d_in[13];
  const float* bh1         = (const float*)d_in[14];
  const float* wh2         = (const float*)d_in[15];
  const float* bh2         = (const float*)d_in[16];
  int E = in_sizes[1] / 2;
  const int* srcp = edge_index;
  const int* dstp = edge_index + E;
  int Q = (E + 3) / 4;

  char* w = (char*)d_ws;
  float* x       = (float*)w; w += (size_t)NN * DD * 4;
  unsigned short* xhf = (unsigned short*)w; w += (size_t)NN * DD * 2;
  short* aggH    = (short*)w; w += (size_t)NPAD * DD * 2;
  short* aggL    = (short*)w; w += (size_t)NPAD * DD * 2;
  short* wph     = (short*)w; w += (size_t)4 * 16384 * 2;
  short* wpl     = (short*)w; w += (size_t)4 * 16384 * 2;
  float* sd      = (float*)w; w += (size_t)NN * 4;
  float* ssb     = (float*)w; w += (size_t)NN * 4;
  float* selfsc  = (float*)w; w += (size_t)NN * 4;
  float* coef    = (float*)w; w += (size_t)NN * 4;
  int*   cnt     = (int*)  w; w += (size_t)NN * 4;
  int*   row_ptr = (int*)  w; w += (size_t)(NN + 8) * 4;
  int*   cursor  = (int*)  w; w += (size_t)NN * 4;
  int*   bsum    = (int*)  w; w += (size_t)64 * 4;
  unsigned* csr  = (unsigned*)w; w += (size_t)E * 4;
  float* csr_w   = (float*)w; w += (size_t)E * 4;
  float* gsum    = (float*)w; w += (size_t)GG * DD * 4;
  int*   gcnt    = (int*)  w; w += (size_t)GG * 4;

  hipMemsetAsync(cnt, 0, (size_t)NN * 4, stream);
  hipMemsetAsync(gsum, 0, (size_t)GG * DD * 4, stream);

  count_kernel<<<(Q + 255) / 256, 256, 0, stream>>>(dstp, cnt, E, Q);
  scan1_kernel<<<NBLK, 256, 0, stream>>>(cnt, row_ptr, bsum);
  scan2_kernel<<<1, 64, 0, stream>>>(bsum, row_ptr);
  scan3_kernel<<<NBLK, 256, 0, stream>>>(bsum, row_ptr, cursor);
  scatter_kernel<<<(Q + 255) / 256, 256, 0, stream>>>(srcp, dstp, edge_weight, cursor, csr, E, Q);
  pack_w_kernel<<<256, 256, 0, stream>>>(w1, w2, wph, wpl);
  gather_ln_kernel<<<(NN + 3) / 4, 256, 0, stream>>>(node_ids, emb, ln_g, ln_b, att_w,
                                                     x, xhf, sd, ssb, selfsc);

  int mlp_grid = (NN + 63) / 64;
  // layer 0
  wgt_kernel <<<(NN + 3) / 4, 256, 0, stream>>>(row_ptr, csr, sd, ssb, selfsc, eps, 0, csr_w, coef);
  agg2_kernel<<<(NN + 3) / 4, 256, 0, stream>>>(x, xhf, row_ptr, csr, csr_w, coef, aggH, aggL);
  mlp_mfma_kernel<0><<<mlp_grid, 256, 0, stream>>>(aggH, aggL,
      wph, wpl, wph + 16384, wpl + 16384, b1, b2,
      ln_g + DD, ln_b + DD, att_w + 2 * DD, x, xhf, sd, ssb, selfsc);
  // layer 1
  wgt_kernel <<<(NN + 3) / 4, 256, 0, stream>>>(row_ptr, csr, sd, ssb, selfsc, eps, 1, csr_w, coef);
  agg2_kernel<<<(NN + 3) / 4, 256, 0, stream>>>(x, xhf, row_ptr, csr, csr_w, coef, aggH, aggL);
  mlp_mfma_kernel<1><<<mlp_grid, 256, 0, stream>>>(aggH, aggL,
      wph + 2 * 16384, wpl + 2 * 16384, wph + 3 * 16384, wpl + 3 * 16384,
      b1 + DD, b2 + DD, ln_g + DD, ln_b + DD, att_w + 2 * DD, x, xhf, sd, ssb, selfsc);

  pool_kernel<<<GG * 16, 128, 0, stream>>>(x, batch, gsum, gcnt);
  head_kernel<<<1, 256, 0, stream>>>(gsum, gcnt, wh1, bh1, wh2, bh2, (float*)d_out);
}

// Round 15
// 412.933 us; speedup vs baseline: 1.0211x; 1.0211x over previous
//
#include <hip/hip_runtime.h>

#define NN 50000
#define NPAD 50048
#define DD 128
#define GG 64
#define NBLK 49   // ceil(NN/1024)

typedef __attribute__((ext_vector_type(8))) short short8;
typedef __attribute__((ext_vector_type(8))) unsigned short ushort8;
typedef __attribute__((ext_vector_type(4))) float f32x4;

__device__ __forceinline__ unsigned short f2bf(float f){
  union { float f; unsigned u; } x; x.f = f;
  unsigned r = x.u + 0x7fffu + ((x.u >> 16) & 1u);
  return (unsigned short)(r >> 16);
}
__device__ __forceinline__ float bf2f(unsigned short h){
  union { unsigned u; float f; } x; x.u = ((unsigned)h) << 16;
  return x.f;
}
// fp16: half-ulp 2^-12
__device__ __forceinline__ unsigned short f2h(float f){
  union { _Float16 h; unsigned short u; } x; x.h = (_Float16)f; return x.u;
}
__device__ __forceinline__ float h2f(unsigned short u){
  union { _Float16 h; unsigned short u; } x; x.u = u; return (float)x.h;
}
__device__ __forceinline__ f32x4 mfma16(short8 a, short8 b, f32x4 c){
  return __builtin_amdgcn_mfma_f32_16x16x32_bf16(a, b, c, 0, 0, 0);
}

__device__ __forceinline__ float wave_reduce_sum(float v){
  #pragma unroll
  for (int off = 32; off; off >>= 1) v += __shfl_xor(v, off, 64);
  return v;
}
__device__ __forceinline__ float wave_reduce_max(float v){
  #pragma unroll
  for (int off = 32; off; off >>= 1) v = fmaxf(v, __shfl_xor(v, off, 64));
  return v;
}

// ---------- fused gather + LayerNorm(l0) + attention dots; writes x fp32 + xhf fp16 ----------
__global__ __launch_bounds__(256) void gather_ln_kernel(const int* __restrict__ ids,
    const float* __restrict__ emb,
    const float* __restrict__ gamma, const float* __restrict__ beta,
    const float* __restrict__ aw,
    float* __restrict__ x, unsigned short* __restrict__ xhf,
    float* __restrict__ sd, float* __restrict__ ss, float* __restrict__ selfsc){
  int n = (blockIdx.x * 256 + threadIdx.x) >> 6;
  int lane = threadIdx.x & 63;
  if (n >= NN) return;
  int id = ids[n];
  float2 v = *(const float2*)&emb[(size_t)id * DD + lane * 2];
  float s  = wave_reduce_sum(v.x + v.y);
  float sq = wave_reduce_sum(v.x * v.x + v.y * v.y);
  float mu  = s * (1.0f / 128.0f);
  float var = sq * (1.0f / 128.0f) - mu * mu;
  float rs  = rsqrtf(var + 1e-5f);
  float2 g = *(const float2*)&gamma[lane * 2];
  float2 b = *(const float2*)&beta[lane * 2];
  float2 y;
  y.x = (v.x - mu) * rs * g.x + b.x;
  y.y = (v.y - mu) * rs * g.y + b.y;
  *(float2*)&x[(size_t)n * DD + lane * 2] = y;
  unsigned pk = (unsigned)f2h(y.x) | ((unsigned)f2h(y.y) << 16);
  ((unsigned*)xhf)[(size_t)n * 64 + lane] = pk;
  float2 a1 = *(const float2*)&aw[lane * 2];
  float2 a2 = *(const float2*)&aw[DD + lane * 2];
  float pd = wave_reduce_sum(y.x * a1.x + y.y * a1.y);
  float ps = wave_reduce_sum(y.x * a2.x + y.y * a2.y);
  if (lane == 0){
    sd[n] = pd; ss[n] = ps;
    float sc = pd + ps;
    selfsc[n] = sc >= 0.f ? sc : 0.2f * sc;
  }
}

// ---------- pack W into MFMA B-fragment order, split bf16 hi/lo ----------
__global__ __launch_bounds__(256) void pack_w_kernel(const float* __restrict__ w1,
    const float* __restrict__ w2, short* __restrict__ wph, short* __restrict__ wpl){
  int i = blockIdx.x * 256 + threadIdx.x;   // 65536 total
  int m = i >> 14, k = (i >> 7) & 127, c = i & 127;
  const float* src = (m & 1) ? w2 : w1;
  float v = src[((size_t)(m >> 1) * 128 + k) * 128 + c];
  unsigned short h = f2bf(v);
  float lo = v - bf2f(h);
  int idx = (m << 14) + ((k >> 3) << 10) + (c << 3) + (k & 7);
  wph[idx] = (short)h;
  wpl[idx] = (short)f2bf(lo);
}

// ---------- CSR build: count with 4-edge ILP ----------
__global__ __launch_bounds__(256) void count_kernel(const int* __restrict__ dst,
    int* __restrict__ cnt, int E, int Q){
  int t = blockIdx.x * 256 + threadIdx.x;
  if (t >= Q) return;
  int e0 = t, e1 = t + Q, e2 = t + 2 * Q, e3 = t + 3 * Q;
  int d0 = (e0 < E) ? dst[e0] : -1;
  int d1 = (e1 < E) ? dst[e1] : -1;
  int d2 = (e2 < E) ? dst[e2] : -1;
  int d3 = (e3 < E) ? dst[e3] : -1;
  if (d0 >= 0) atomicAdd(&cnt[d0], 1);
  if (d1 >= 0) atomicAdd(&cnt[d1], 1);
  if (d2 >= 0) atomicAdd(&cnt[d2], 1);
  if (d3 >= 0) atomicAdd(&cnt[d3], 1);
}

__global__ __launch_bounds__(256) void scan1_kernel(const int* __restrict__ cnt,
    int* __restrict__ rp, int* __restrict__ bsum){
  __shared__ int wsum[4];
  int tid = threadIdx.x, lane = tid & 63, wid = tid >> 6;
  int base = blockIdx.x * 1024 + tid * 4;
  int4 v = {0,0,0,0};
  if (base < NN) v = *(const int4*)&cnt[base];
  int tsum = v.x + v.y + v.z + v.w;
  int incl = tsum;
  #pragma unroll
  for (int off = 1; off < 64; off <<= 1){
    int t = __shfl_up(incl, off, 64);
    if (lane >= off) incl += t;
  }
  if (lane == 63) wsum[wid] = incl;
  __syncthreads();
  int woff = 0;
  for (int w = 0; w < wid; ++w) woff += wsum[w];
  int excl = woff + incl - tsum;
  if (base < NN){
    int4 o;
    o.x = excl; o.y = excl + v.x; o.z = excl + v.x + v.y; o.w = excl + v.x + v.y + v.z;
    *(int4*)&rp[base] = o;
  }
  if (tid == 0) bsum[blockIdx.x] = wsum[0] + wsum[1] + wsum[2] + wsum[3];
}

__global__ __launch_bounds__(64) void scan2_kernel(int* __restrict__ bsum, int* __restrict__ rp){
  int lane = threadIdx.x;
  int v = (lane < NBLK) ? bsum[lane] : 0;
  int incl = v;
  #pragma unroll
  for (int off = 1; off < 64; off <<= 1){
    int t = __shfl_up(incl, off, 64);
    if (lane >= off) incl += t;
  }
  if (lane < NBLK) bsum[lane] = incl - v;
  if (lane == 63) rp[NN] = incl;
}

__global__ __launch_bounds__(256) void scan3_kernel(const int* __restrict__ bsum,
    int* __restrict__ rp, int* __restrict__ cursor){
  int base = blockIdx.x * 1024 + threadIdx.x * 4;
  if (base >= NN) return;
  int add = bsum[blockIdx.x];
  int4 t = *(const int4*)&rp[base];
  t.x += add; t.y += add; t.z += add; t.w += add;
  *(int4*)&rp[base] = t;
  *(int4*)&cursor[base] = t;
}

// ---------- scatter: 4 edges/thread ILP; 4B record {u16 src | fp16 ew} ----------
__global__ __launch_bounds__(256) void scatter_kernel(const int* __restrict__ src,
    const int* __restrict__ dst, const float* __restrict__ ew,
    int* __restrict__ cursor, unsigned* __restrict__ csr, int E, int Q){
  int t = blockIdx.x * 256 + threadIdx.x;
  if (t >= Q) return;
  int e0 = t, e1 = t + Q, e2 = t + 2 * Q, e3 = t + 3 * Q;
  int d0 = (e0 < E) ? dst[e0] : -1;
  int d1 = (e1 < E) ? dst[e1] : -1;
  int d2 = (e2 < E) ? dst[e2] : -1;
  int d3 = (e3 < E) ? dst[e3] : -1;
  unsigned r0 = 0, r1 = 0, r2 = 0, r3 = 0;
  if (d0 >= 0) r0 = (unsigned)src[e0] | ((unsigned)f2h(ew[e0]) << 16);
  if (d1 >= 0) r1 = (unsigned)src[e1] | ((unsigned)f2h(ew[e1]) << 16);
  if (d2 >= 0) r2 = (unsigned)src[e2] | ((unsigned)f2h(ew[e2]) << 16);
  if (d3 >= 0) r3 = (unsigned)src[e3] | ((unsigned)f2h(ew[e3]) << 16);
  int p0 = (d0 >= 0) ? atomicAdd(&cursor[d0], 1) : 0;
  int p1 = (d1 >= 0) ? atomicAdd(&cursor[d1], 1) : 0;
  int p2 = (d2 >= 0) ? atomicAdd(&cursor[d2], 1) : 0;
  int p3 = (d3 >= 0) ? atomicAdd(&cursor[d3], 1) : 0;
  if (d0 >= 0) csr[p0] = r0;
  if (d1 >= 0) csr[p1] = r1;
  if (d2 >= 0) csr[p2] = r2;
  if (d3 >= 0) csr[p3] = r3;
}

// ---------- per-node softmax stats + per-edge weight precompute (split, R8 structure) ----------
__global__ __launch_bounds__(256) void wgt_kernel(
    const int* __restrict__ row_ptr, const unsigned* __restrict__ csr,
    const float* __restrict__ sd, const float* __restrict__ ss,
    const float* __restrict__ selfsc,
    const float* __restrict__ eps_arr, int layer,
    float* __restrict__ csr_w, float* __restrict__ coef){
  int n = (blockIdx.x * 256 + threadIdx.x) >> 6;
  int lane = threadIdx.x & 63;
  if (n >= NN) return;
  int beg = row_ptr[n], end = row_ptr[n + 1];
  float sdn = sd[n];
  float sf = selfsc[n];
  float m = sf;
  for (int j = beg + lane; j < end; j += 64){
    unsigned e = csr[j];
    float sc = sdn + ss[e & 0xFFFFu];
    sc = sc >= 0.f ? sc : 0.2f * sc;
    m = fmaxf(m, sc);
  }
  m = wave_reduce_max(m);
  float dsum = 0.f;
  for (int j = beg + lane; j < end; j += 64){
    unsigned e = csr[j];
    float sc = sdn + ss[e & 0xFFFFu];
    sc = sc >= 0.f ? sc : 0.2f * sc;
    dsum += expf(sc - m);
  }
  dsum = wave_reduce_sum(dsum);
  float exself = expf(sf - m);
  dsum += exself;
  float inv = 1.0f / (dsum + 1e-16f);
  for (int j = beg + lane; j < end; j += 64){
    unsigned e = csr[j];
    float sc = sdn + ss[e & 0xFFFFu];
    sc = sc >= 0.f ? sc : 0.2f * sc;
    csr_w[j] = expf(sc - m) * inv * h2f((unsigned short)(e >> 16));
  }
  if (lane == 0) coef[n] = 1.0f + eps_arr[layer] + exself * inv;
}

// ---------- gather-aggregate (fp16 messages) + GIN self term (fp32); writes bf16 hi/lo ----------
__global__ __launch_bounds__(256) void agg2_kernel(const float* __restrict__ x,
    const unsigned short* __restrict__ xhf,
    const int* __restrict__ row_ptr, const unsigned* __restrict__ csr,
    const float* __restrict__ csr_w,
    const float* __restrict__ coef, short* __restrict__ aggH, short* __restrict__ aggL){
  int n = (blockIdx.x * 256 + threadIdx.x) >> 6;
  int lane = threadIdx.x & 63;
  if (n >= NN) return;
  int grp = lane >> 4, sub = lane & 15;
  int beg = row_ptr[n], end = row_ptr[n + 1];
  float a[8] = {0,0,0,0,0,0,0,0};
  int j = beg + grp;
  for (; j + 4 < end; j += 8){
    int   s0 = csr[j] & 0xFFFFu;     float w0 = csr_w[j];
    int   s1 = csr[j + 4] & 0xFFFFu; float w1 = csr_w[j + 4];
    ushort8 u0 = *(const ushort8*)&xhf[(size_t)s0 * DD + sub * 8];
    ushort8 u1 = *(const ushort8*)&xhf[(size_t)s1 * DD + sub * 8];
    #pragma unroll
    for (int i = 0; i < 8; ++i) a[i] = fmaf(w0, h2f(u0[i]), a[i]);
    #pragma unroll
    for (int i = 0; i < 8; ++i) a[i] = fmaf(w1, h2f(u1[i]), a[i]);
  }
  if (j < end){
    int s0 = csr[j] & 0xFFFFu; float w0 = csr_w[j];
    ushort8 u0 = *(const ushort8*)&xhf[(size_t)s0 * DD + sub * 8];
    #pragma unroll
    for (int i = 0; i < 8; ++i) a[i] = fmaf(w0, h2f(u0[i]), a[i]);
  }
  #pragma unroll
  for (int mask = 16; mask <= 32; mask <<= 1){
    #pragma unroll
    for (int i = 0; i < 8; ++i) a[i] += __shfl_xor(a[i], mask, 64);
  }
  if (grp == 0){
    float c = coef[n];
    const float4* xr = (const float4*)&x[(size_t)n * DD + sub * 8];
    float4 x0 = xr[0], x1 = xr[1];
    a[0] = fmaf(c, x0.x, a[0]); a[1] = fmaf(c, x0.y, a[1]);
    a[2] = fmaf(c, x0.z, a[2]); a[3] = fmaf(c, x0.w, a[3]);
    a[4] = fmaf(c, x1.x, a[4]); a[5] = fmaf(c, x1.y, a[5]);
    a[6] = fmaf(c, x1.z, a[6]); a[7] = fmaf(c, x1.w, a[7]);
    short8 H, L;
    #pragma unroll
    for (int i = 0; i < 8; ++i){
      unsigned short h = f2bf(a[i]);
      H[i] = (short)h;
      L[i] = (short)f2bf(a[i] - bf2f(h));
    }
    *(short8*)&aggH[(size_t)n * DD + sub * 8] = H;
    *(short8*)&aggL[(size_t)n * DD + sub * 8] = L;
  }
}

// ---------- MFMA conv MLP: 16-row blocks, 4 waves column-split (wave w owns cols w*32..w*32+31)
// Grid = NN/16 = 3125 blocks -> 12.5K waves for latency hiding via TLP.
template<int MODE>
__global__ __launch_bounds__(256) void mlp_mfma_kernel(
    const short* __restrict__ aH, const short* __restrict__ aL,
    const short* __restrict__ w1h, const short* __restrict__ w1l,
    const short* __restrict__ w2h, const short* __restrict__ w2l,
    const float* __restrict__ B1, const float* __restrict__ B2,
    const float* __restrict__ g2, const float* __restrict__ be2,
    const float* __restrict__ aw2,
    float* __restrict__ xout, unsigned short* __restrict__ xhf,
    float* __restrict__ sd, float* __restrict__ ss,
    float* __restrict__ selfsc){
  __shared__ __align__(16) short hh[16 * DD];
  __shared__ __align__(16) short hl[16 * DD];
  __shared__ float red0[4][16];
  __shared__ float red1[4][16];
  int tid = threadIdx.x;
  int w = tid >> 6, l = tid & 63;
  int g = l >> 4, c16 = l & 15;
  int base = blockIdx.x * 16;          // NN = 3125*16 exactly
  int rowA = base + c16;

  short8 a1h[4], a1l[4];
  #pragma unroll
  for (int ks = 0; ks < 4; ++ks){
    size_t off = (size_t)rowA * DD + ks * 32 + g * 8;
    a1h[ks] = *(const short8*)(aH + off);
    a1l[ks] = *(const short8*)(aL + off);
  }

  f32x4 acc[2];
  // ---- GEMM1: wave computes its 2 ct tiles ----
  #pragma unroll
  for (int cti = 0; cti < 2; ++cti){
    int ct = w * 2 + cti;
    f32x4 a = {0.f, 0.f, 0.f, 0.f};
    #pragma unroll
    for (int ks = 0; ks < 4; ++ks){
      int bo = (((ks * 4 + g) * 128) + ct * 16 + c16) * 8;
      short8 bh = *(const short8*)(w1h + bo);
      short8 bl = *(const short8*)(w1l + bo);
      a = mfma16(a1h[ks], bh, a);
      a = mfma16(a1l[ks], bh, a);
      a = mfma16(a1h[ks], bl, a);
    }
    acc[cti] = a;
  }

  // epilogue 1: bias + relu, split to bf16 hi/lo in swizzled LDS (shared across waves)
  #pragma unroll
  for (int cti = 0; cti < 2; ++cti){
    int col = (w * 2 + cti) * 16 + c16;
    float b = B1[col];
    #pragma unroll
    for (int r = 0; r < 4; ++r){
      int rl = g * 4 + r;
      float v = acc[cti][r] + b;
      v = v > 0.f ? v : 0.f;
      unsigned short h = f2bf(v);
      int idx = rl * DD + ((((col >> 3) ^ (rl & 7))) << 3) + (col & 7);
      hh[idx] = (short)h;
      hl[idx] = (short)f2bf(v - bf2f(h));
    }
  }
  __syncthreads();

  int rowL = c16;
  short8 a2h[4], a2l[4];
  #pragma unroll
  for (int ks = 0; ks < 4; ++ks){
    int chunk = ks * 4 + g;
    int idx = rowL * DD + ((chunk ^ (rowL & 7)) << 3);
    a2h[ks] = *(const short8*)&hh[idx];
    a2l[ks] = *(const short8*)&hl[idx];
  }

  // ---- GEMM2 ----
  #pragma unroll
  for (int cti = 0; cti < 2; ++cti){
    int ct = w * 2 + cti;
    f32x4 a = {0.f, 0.f, 0.f, 0.f};
    #pragma unroll
    for (int ks = 0; ks < 4; ++ks){
      int bo = (((ks * 4 + g) * 128) + ct * 16 + c16) * 8;
      short8 bh = *(const short8*)(w2h + bo);
      short8 bl = *(const short8*)(w2l + bo);
      a = mfma16(a2h[ks], bh, a);
      a = mfma16(a2l[ks], bh, a);
      a = mfma16(a2h[ks], bl, a);
    }
    acc[cti] = a;
  }

  #pragma unroll
  for (int cti = 0; cti < 2; ++cti){
    int col = (w * 2 + cti) * 16 + c16;
    float b = B2[col];
    #pragma unroll
    for (int r = 0; r < 4; ++r){
      float v = acc[cti][r] + b;
      acc[cti][r] = v > 0.f ? v : 0.f;
    }
  }

  if (MODE == 1){
    #pragma unroll
    for (int cti = 0; cti < 2; ++cti){
      int col = (w * 2 + cti) * 16 + c16;
      #pragma unroll
      for (int r = 0; r < 4; ++r){
        int row = base + g * 4 + r;
        xout[(size_t)row * DD + col] = acc[cti][r];
      }
    }
  } else {
    // LN across 128 cols: per-wave 32-col partials -> cross-wave LDS reduction
    float s_p[4] = {0,0,0,0}, q_p[4] = {0,0,0,0};
    #pragma unroll
    for (int cti = 0; cti < 2; ++cti)
      #pragma unroll
      for (int r = 0; r < 4; ++r){ float v = acc[cti][r]; s_p[r] += v; q_p[r] += v * v; }
    #pragma unroll
    for (int off = 1; off < 16; off <<= 1){
      #pragma unroll
      for (int r = 0; r < 4; ++r){
        s_p[r] += __shfl_xor(s_p[r], off, 64);
        q_p[r] += __shfl_xor(q_p[r], off, 64);
      }
    }
    if (c16 == 0){
      #pragma unroll
      for (int r = 0; r < 4; ++r){
        red0[w][g * 4 + r] = s_p[r];
        red1[w][g * 4 + r] = q_p[r];
      }
    }
    __syncthreads();
    float mu[4], rs[4];
    #pragma unroll
    for (int r = 0; r < 4; ++r){
      int rt = g * 4 + r;
      float S = (red0[0][rt] + red0[1][rt]) + (red0[2][rt] + red0[3][rt]);
      float Q = (red1[0][rt] + red1[1][rt]) + (red1[2][rt] + red1[3][rt]);
      mu[r] = S * (1.f / 128.f);
      float var = Q * (1.f / 128.f) - mu[r] * mu[r];
      rs[r] = rsqrtf(var + 1e-5f);
    }
    __syncthreads();   // red0/red1 about to be reused
    float pd_p[4] = {0,0,0,0}, ps_p[4] = {0,0,0,0};
    #pragma unroll
    for (int cti = 0; cti < 2; ++cti){
      int col = (w * 2 + cti) * 16 + c16;
      float gam = g2[col], bet = be2[col];
      float aa = aw2[col], ab = aw2[DD + col];
      #pragma unroll
      for (int r = 0; r < 4; ++r){
        float y = (acc[cti][r] - mu[r]) * rs[r] * gam + bet;
        acc[cti][r] = y;
        pd_p[r] += y * aa; ps_p[r] += y * ab;
      }
    }
    #pragma unroll
    for (int off = 1; off < 16; off <<= 1){
      #pragma unroll
      for (int r = 0; r < 4; ++r){
        pd_p[r] += __shfl_xor(pd_p[r], off, 64);
        ps_p[r] += __shfl_xor(ps_p[r], off, 64);
      }
    }
    if (c16 == 0){
      #pragma unroll
      for (int r = 0; r < 4; ++r){
        red0[w][g * 4 + r] = pd_p[r];
        red1[w][g * 4 + r] = ps_p[r];
      }
    }
    __syncthreads();
    #pragma unroll
    for (int cti = 0; cti < 2; ++cti){
      int col = (w * 2 + cti) * 16 + c16;
      #pragma unroll
      for (int r = 0; r < 4; ++r){
        int row = base + g * 4 + r;
        float y = acc[cti][r];
        xout[(size_t)row * DD + col] = y;
        xhf[(size_t)row * DD + col] = f2h(y);
      }
    }
    if (w == 0 && c16 == 0){
      #pragma unroll
      for (int r = 0; r < 4; ++r){
        int rt = g * 4 + r;
        int row = base + rt;
        float pd = (red0[0][rt] + red0[1][rt]) + (red0[2][rt] + red0[3][rt]);
        float ps = (red1[0][rt] + red1[1][rt]) + (red1[2][rt] + red1[3][rt]);
        sd[row] = pd; ss[row] = ps;
        float sc = pd + ps;
        selfsc[row] = sc >= 0.f ? sc : 0.2f * sc;
      }
    }
  }
}

// ---------- global mean pool (16 parts/graph, 4-way unrolled) ----------
__global__ __launch_bounds__(128) void pool_kernel(const float* __restrict__ x,
    const int* __restrict__ batch, float* __restrict__ gsum, int* __restrict__ gcnt){
  int g = blockIdx.x >> 4, part = blockIdx.x & 15;
  int lo = 0, hi = NN;
  while (lo < hi){ int mid = (lo + hi) >> 1; if (batch[mid] < g) lo = mid + 1; else hi = mid; }
  int beg = lo;
  lo = beg; hi = NN;
  while (lo < hi){ int mid = (lo + hi) >> 1; if (batch[mid] < g + 1) lo = mid + 1; else hi = mid; }
  int end = lo;
  int cg = end - beg;
  int rb = beg + (int)((long long)cg * part / 16);
  int re = beg + (int)((long long)cg * (part + 1) / 16);
  int d = threadIdx.x;
  float s0 = 0.f, s1 = 0.f, s2 = 0.f, s3 = 0.f;
  int r = rb;
  for (; r + 3 < re; r += 4){
    s0 += x[(size_t)r * DD + d];
    s1 += x[(size_t)(r + 1) * DD + d];
    s2 += x[(size_t)(r + 2) * DD + d];
    s3 += x[(size_t)(r + 3) * DD + d];
  }
  for (; r < re; ++r) s0 += x[(size_t)r * DD + d];
  float sum = (s0 + s1) + (s2 + s3);
  atomicAdd(&gsum[g * DD + d], sum);
  if (d == 0 && part == 0) gcnt[g] = cg;
}

// ---------- head MLP ----------
__global__ __launch_bounds__(256) void head_kernel(const float* __restrict__ gsum,
    const int* __restrict__ gcnt,
    const float* __restrict__ wh1, const float* __restrict__ bh1,
    const float* __restrict__ wh2, const float* __restrict__ bh2,
    float* __restrict__ outp){
  __shared__ float gm[GG * DD];
  __shared__ float h[GG * 64];
  int tid = threadIdx.x;
  for (int i = tid; i < GG * DD; i += 256){
    int g = i >> 7;
    int c = gcnt[g];
    gm[i] = gsum[i] / (float)(c > 0 ? c : 1);
  }
  __syncthreads();
  for (int i = tid; i < GG * 64; i += 256){
    int r = i >> 6, c = i & 63;
    float a0 = 0.f, a1 = 0.f;
    for (int k = 0; k < DD; k += 2){
      a0 = fmaf(gm[r * DD + k],     wh1[k * 64 + c],       a0);
      a1 = fmaf(gm[r * DD + k + 1], wh1[(k + 1) * 64 + c], a1);
    }
    float v = a0 + a1 + bh1[c];
    h[i] = v > 0.f ? v : 0.f;
  }
  __syncthreads();
  if (tid < GG * 2){
    int r = tid >> 1, c = tid & 1;
    float a = 0.f;
    for (int k = 0; k < 64; ++k) a = fmaf(h[r * 64 + k], wh2[k * 2 + c], a);
    outp[tid] = a + bh2[c];
  }
}

extern "C" void kernel_launch(void* const* d_in, const int* in_sizes, int n_in,
                              void* d_out, int out_size, void* d_ws, size_t ws_size,
                              hipStream_t stream){
  const int*   node_ids    = (const int*)  d_in[0];
  const int*   edge_index  = (const int*)  d_in[1];
  const float* edge_weight = (const float*)d_in[2];
  const int*   batch       = (const int*)  d_in[3];
  const float* emb         = (const float*)d_in[4];
  const float* ln_g        = (const float*)d_in[5];
  const float* ln_b        = (const float*)d_in[6];
  const float* att_w       = (const float*)d_in[7];
  const float* w1          = (const float*)d_in[8];
  const float* b1          = (const float*)d_in[9];
  const float* w2          = (const float*)d_in[10];
  const float* b2          = (const float*)d_in[11];
  const float* eps         = (const float*)d_in[12];
  const float* wh1         = (const float*)d_in[13];
  const float* bh1         = (const float*)d_in[14];
  const float* wh2         = (const float*)d_in[15];
  const float* bh2         = (const float*)d_in[16];
  int E = in_sizes[1] / 2;
  const int* srcp = edge_index;
  const int* dstp = edge_index + E;
  int Q = (E + 3) / 4;

  char* w = (char*)d_ws;
  float* x       = (float*)w; w += (size_t)NN * DD * 4;
  unsigned short* xhf = (unsigned short*)w; w += (size_t)NN * DD * 2;
  short* aggH    = (short*)w; w += (size_t)NPAD * DD * 2;
  short* aggL    = (short*)w; w += (size_t)NPAD * DD * 2;
  short* wph     = (short*)w; w += (size_t)4 * 16384 * 2;
  short* wpl     = (short*)w; w += (size_t)4 * 16384 * 2;
  float* sd      = (float*)w; w += (size_t)NN * 4;
  float* ssb     = (float*)w; w += (size_t)NN * 4;
  float* selfsc  = (float*)w; w += (size_t)NN * 4;
  float* coef    = (float*)w; w += (size_t)NN * 4;
  int*   cnt     = (int*)  w; w += (size_t)NN * 4;
  int*   row_ptr = (int*)  w; w += (size_t)(NN + 8) * 4;
  int*   cursor  = (int*)  w; w += (size_t)NN * 4;
  int*   bsum    = (int*)  w; w += (size_t)64 * 4;
  unsigned* csr  = (unsigned*)w; w += (size_t)E * 4;
  float* csr_w   = (float*)w; w += (size_t)E * 4;
  float* gsum    = (float*)w; w += (size_t)GG * DD * 4;
  int*   gcnt    = (int*)  w; w += (size_t)GG * 4;

  hipMemsetAsync(cnt, 0, (size_t)NN * 4, stream);
  hipMemsetAsync(gsum, 0, (size_t)GG * DD * 4, stream);

  count_kernel<<<(Q + 255) / 256, 256, 0, stream>>>(dstp, cnt, E, Q);
  scan1_kernel<<<NBLK, 256, 0, stream>>>(cnt, row_ptr, bsum);
  scan2_kernel<<<1, 64, 0, stream>>>(bsum, row_ptr);
  scan3_kernel<<<NBLK, 256, 0, stream>>>(bsum, row_ptr, cursor);
  scatter_kernel<<<(Q + 255) / 256, 256, 0, stream>>>(srcp, dstp, edge_weight, cursor, csr, E, Q);
  pack_w_kernel<<<256, 256, 0, stream>>>(w1, w2, wph, wpl);
  gather_ln_kernel<<<(NN + 3) / 4, 256, 0, stream>>>(node_ids, emb, ln_g, ln_b, att_w,
                                                     x, xhf, sd, ssb, selfsc);

  int mlp_grid = (NN + 15) / 16;   // 3125
  // layer 0
  wgt_kernel <<<(NN + 3) / 4, 256, 0, stream>>>(row_ptr, csr, sd, ssb, selfsc, eps, 0, csr_w, coef);
  agg2_kernel<<<(NN + 3) / 4, 256, 0, stream>>>(x, xhf, row_ptr, csr, csr_w, coef, aggH, aggL);
  mlp_mfma_kernel<0><<<mlp_grid, 256, 0, stream>>>(aggH, aggL,
      wph, wpl, wph + 16384, wpl + 16384, b1, b2,
      ln_g + DD, ln_b + DD, att_w + 2 * DD, x, xhf, sd, ssb, selfsc);
  // layer 1
  wgt_kernel <<<(NN + 3) / 4, 256, 0, stream>>>(row_ptr, csr, sd, ssb, selfsc, eps, 1, csr_w, coef);
  agg2_kernel<<<(NN + 3) / 4, 256, 0, stream>>>(x, xhf, row_ptr, csr, csr_w, coef, aggH, aggL);
  mlp_mfma_kernel<1><<<mlp_grid, 256, 0, stream>>>(aggH, aggL,
      wph + 2 * 16384, wpl + 2 * 16384, wph + 3 * 16384, wpl + 3 * 16384,
      b1 + DD, b2 + DD, ln_g + DD, ln_b + DD, att_w + 2 * DD, x, xhf, sd, ssb, selfsc);

  pool_kernel<<<GG * 16, 128, 0, stream>>>(x, batch, gsum, gcnt);
  head_kernel<<<1, 256, 0, stream>>>(gsum, gcnt, wh1, bh1, wh2, bh2, (float*)d_out);
}